// Round 7
// baseline (115.862 us; speedup 1.0000x reference)
//
#include <hip/hip_runtime.h>
#include <hip/hip_bf16.h>

typedef unsigned short u16;
typedef __attribute__((ext_vector_type(8))) short short8;
typedef __attribute__((ext_vector_type(4))) float floatx4;

#define NROWS 8192
#define DIM 256

__device__ __forceinline__ void atomicMinFloat(float* addr, float val) {
    if (val >= 0.0f) {
        atomicMin((int*)addr, __float_as_int(val));
    } else {
        atomicMax((unsigned int*)addr, __float_as_uint(val));
    }
}

__device__ __forceinline__ u16 f32_to_bf16_rne(float x) {
    unsigned int u = __float_as_uint(x);
    unsigned int r = (u + 0x7fffu + ((u >> 16) & 1u)) >> 16;
    return (u16)r;
}

// C(M) = -logp * exp(logp); quasiconcave in M => rowmin = min(C(minM), C(maxM)).
__device__ __forceinline__ float c_of_m(float m) {
    const float INV_SIG = 1.0f / 0.3f;
    const float KC = 0.28503427f;  // -ln(0.3) - 0.5*ln(2*pi)
    float z = (m - 1.0f) * INV_SIG;
    float logp = fmaf(-0.5f * z, z, KC);
    return -logp * __expf(logp);
}

// 16B async DMA global -> LDS. LDS dest is wave-uniform base + lane*16.
__device__ __forceinline__ void load16(const u16* g, u16* l) {
    __builtin_amdgcn_global_load_lds(
        (__attribute__((address_space(1))) void*)g,
        (__attribute__((address_space(3))) void*)l, 16, 0, 0);
}

// Normalize rows (L2-norm clamped at 1e-8), wave per row, float4 loads.
// BOTH X and Y are written in MFMA fragment ("panel") layout:
//   element (row r, k) -> flat[ ((p*8+kt)*64 + lq*16 + lm)*8 + j ]
//   p=r>>4, lm=r&15, kt=k>>5, lq=(k>>3)&3, j=k&7.
// A fragment load is then base + lane*16B: one coalesced dwordx4.
// Verified end-to-end R5/R11/R14/R15 (absmax 1.5e-5).
__global__ __launch_bounds__(256) void normalize_kernel(const float* __restrict__ Ex,
                                                        const float* __restrict__ Ey,
                                                        u16* __restrict__ Xs,
                                                        u16* __restrict__ Ys,
                                                        float* __restrict__ out) {
    const int t = threadIdx.x;
    const int ln = t & 63;
    const int row = blockIdx.x * 4 + (t >> 6);
    const float* src = (blockIdx.y == 0) ? Ex : Ey;
    u16* dst = (blockIdx.y == 0) ? Xs : Ys;

    float4 v = *(const float4*)(src + (size_t)row * DIM + ln * 4);
    float s = fmaf(v.x, v.x, fmaf(v.y, v.y, fmaf(v.z, v.z, v.w * v.w)));
    #pragma unroll
    for (int m = 32; m >= 1; m >>= 1) s += __shfl_xor(s, m, 64);
    float inv = 1.0f / fmaxf(sqrtf(s), 1e-8f);

    ushort4 o;
    o.x = f32_to_bf16_rne(v.x * inv);
    o.y = f32_to_bf16_rne(v.y * inv);
    o.z = f32_to_bf16_rne(v.z * inv);
    o.w = f32_to_bf16_rne(v.w * inv);

    const int p = row >> 4;
    const int lm = row & 15;
    const int kt = ln >> 3;
    const int lq = (ln >> 1) & 3;
    const int j4 = (ln & 1) * 4;
    const size_t off = ((size_t)((p * 8 + kt) * 64 + lq * 16 + lm)) * 8 + j4;
    *(ushort4*)(dst + off) = o;

    if (blockIdx.y == 0 && ln == 0) out[row] = __uint_as_float(0x7f800000u);  // +inf
}

// R23: INSTRUMENTATION ROUND. Five structural variants (R0/R1/R3/R5/R6) all
// pinned at ~40 us GEMM = 859 TF, and the gemm dispatch (<44 us) never
// surfaces in the top-5 counter table (hidden under the 44-49 us harness
// fills). The fold is an idempotent atomicMin, so the ct loop runs TWICE
// (pass 2 recomputes identical M values -- still correct): gemm ~80 us ->
// top-1 with full MfmaUtil/VALUBusy/FETCH/conflict visibility at full
// occupancy. Bundled candidate lever: explicit 2-deep register software
// pipeline of B fragments (bfA/bfB alternation, all indices static after
// unroll -- rule #20), using the ~30 free VGPR R6's 32-col ct created.
// Readout decides R8: MfmaUtil>=48% -> pipeline works, revert to 1 pass and
// keep; ~40% + low VALUBusy -> stall-bound, pipeline dead end; VALUBusy>30%
// -> VALU co-bound, attack fold/addressing.
__global__ void __launch_bounds__(512, 2)
gemm_min_kernel(const u16* __restrict__ Xs,
                const u16* __restrict__ Ys,
                float* __restrict__ out) {
    __shared__ u16 Bs[2][16 * 512];  // 2 x 16 KB

    const int tid = threadIdx.x;
    const int w = tid >> 6;      // 0..7 row-group (64 rows each)
    const int lane = tid & 63;
    const int lq = lane >> 4;
    const int lm = lane & 15;

    // XCD-aware remap (dispatch i -> XCD i&7 round-robin): XCD x gets a
    // 4 row-tile x 8 col-group region. Bijective over the 16x16 grid.
    const int i = blockIdx.x;
    const int x = i & 7;
    const int jj = i >> 3;                      // 0..31 within XCD
    const int rt = (x & 3) * 4 + (jj & 3);      // row-tile 0..15
    const int cgrp = (x >> 2) * 8 + (jj >> 2);  // col-group 0..15

    const int rowStart = rt * 512;
    const int rowPan0 = rt * 32 + w * 4;
    const u16* ycol0 = Ys + (size_t)cgrp * 32 * 4096;  // 16 cts x 8192 u16

    // Stage one 32col x 256k B tile (16 KB = 16 x 1 KB units) via DMA.
    // 8 waves x 2 units; unit u -> (col-panel u>>3, kt u&7); LDS slot u*512
    // so fragment reads are Bs[(cg*8+kt)*512 + lane*8] (b128, conflict-free).
    auto stage1 = [&](int buf, const u16* yb, int iu) {
        const int u = w * 2 + iu;
        load16(yb + (u >> 3) * 4096 + (u & 7) * 512 + lane * 8,
               &Bs[buf][u * 512]);
    };

    short8 a[4][8];
    auto loadA = [&](int kt) {
        #pragma unroll
        for (int rg = 0; rg < 4; ++rg)
            a[rg][kt] = *(const short8*)(
                Xs + ((size_t)(rowPan0 + rg) * 8 + kt) * 512 + lane * 8);
    };

    floatx4 mn4[4], mx4[4];
    #pragma unroll
    for (int rg = 0; rg < 4; ++rg) {
        mn4[rg] = (floatx4){3.4e38f, 3.4e38f, 3.4e38f, 3.4e38f};
        mx4[rg] = (floatx4){-3.4e38f, -3.4e38f, -3.4e38f, -3.4e38f};
    }

    floatx4 acc[4][2];
    const floatx4 FZ = (floatx4){0.0f, 0.0f, 0.0f, 0.0f};

    // Software-pipelined compute: bfA/bfB alternate, next kt's 2 B-frags
    // issue BEFORE the current kt's 8 MFMAs. All indices static (full
    // unroll) so both buffers live in registers.
    auto compute = [&](int buf) {
        const u16* bsb = &Bs[buf][0];
        short8 bfA[2], bfB[2];
        bfA[0] = *(const short8*)(bsb + (0 * 8 + 0) * 512 + lane * 8);
        bfA[1] = *(const short8*)(bsb + (1 * 8 + 0) * 512 + lane * 8);
        #pragma unroll
        for (int k2 = 0; k2 < 4; ++k2) {
            const int ke = 2 * k2;      // even kt, uses bfA
            const int ko = ke + 1;      // odd kt, uses bfB
            bfB[0] = *(const short8*)(bsb + (0 * 8 + ko) * 512 + lane * 8);
            bfB[1] = *(const short8*)(bsb + (1 * 8 + ko) * 512 + lane * 8);
            if (ke == 0) {
                #pragma unroll
                for (int cg = 0; cg < 2; ++cg)
                    #pragma unroll
                    for (int rg = 0; rg < 4; ++rg)
                        acc[rg][cg] = __builtin_amdgcn_mfma_f32_16x16x32_bf16(
                            a[rg][0], bfA[cg], FZ, 0, 0, 0);
            } else {
                #pragma unroll
                for (int cg = 0; cg < 2; ++cg)
                    #pragma unroll
                    for (int rg = 0; rg < 4; ++rg)
                        acc[rg][cg] = __builtin_amdgcn_mfma_f32_16x16x32_bf16(
                            a[rg][ke], bfA[cg], acc[rg][cg], 0, 0, 0);
            }
            if (ko < 7) {
                bfA[0] = *(const short8*)(bsb + (0 * 8 + ko + 1) * 512 + lane * 8);
                bfA[1] = *(const short8*)(bsb + (1 * 8 + ko + 1) * 512 + lane * 8);
            }
            #pragma unroll
            for (int cg = 0; cg < 2; ++cg)
                #pragma unroll
                for (int rg = 0; rg < 4; ++rg)
                    acc[rg][cg] = __builtin_amdgcn_mfma_f32_16x16x32_bf16(
                        a[rg][ko], bfB[cg], acc[rg][cg], 0, 0, 0);
        }
    };
    auto fold = [&]() {
        #pragma unroll
        for (int rg = 0; rg < 4; ++rg)
            #pragma unroll
            for (int cg = 0; cg < 2; ++cg)
                #pragma unroll
                for (int r = 0; r < 4; ++r) {
                    float m = acc[rg][cg][r];
                    mn4[rg][r] = fminf(mn4[rg][r], m);
                    mx4[rg][r] = fmaxf(mx4[rg][r], m);
                }
    };

    // --- ct = 0, peeled: overlap A prologue with B0 DMA ---
    stage1(0, ycol0, 0); stage1(0, ycol0, 1);
    loadA(0); loadA(1);
    __syncthreads();         // drains B0 DMA (+ the early A loads)
    stage1(1, ycol0 + 8192, 0); stage1(1, ycol0 + 8192, 1);  // prefetch ct=1
    loadA(2); loadA(3); loadA(4); loadA(5); loadA(6); loadA(7);
    compute(0);
    fold();

    // --- cts 1..31: TWO passes over the 16 col-tiles (pass 2 recomputes
    // identical M values; atomicMin fold is idempotent -> correct). ---
    #pragma unroll 1
    for (int ct = 1; ct < 32; ++ct) {
        const int buf = ct & 1;
        __syncthreads();           // drains this ct's B DMA (issued a ct ago)
        if (ct < 31) {
            const u16* ynext = ycol0 + (size_t)((ct + 1) & 15) * 8192;
            stage1(buf ^ 1, ynext, 0);
            stage1(buf ^ 1, ynext, 1);
        }
        compute(buf);
        fold();
    }

    // Single epilogue: quad-lane reduce, eval C twice (quasiconcavity),
    // fire-and-forget atomicMin (no read guard -- R3 post-mortem).
    #pragma unroll
    for (int rg = 0; rg < 4; ++rg) {
        #pragma unroll
        for (int r = 0; r < 4; ++r) {
            float mn = mn4[rg][r];
            float mx = mx4[rg][r];
            #pragma unroll
            for (int mofs = 1; mofs < 16; mofs <<= 1) {
                mn = fminf(mn, __shfl_xor(mn, mofs, 64));
                mx = fmaxf(mx, __shfl_xor(mx, mofs, 64));
            }
            if (lm == 0) {
                float cmin = fminf(c_of_m(mn), c_of_m(mx));
                int row = rowStart + w * 64 + rg * 16 + lq * 4 + r;
                atomicMinFloat(&out[row], cmin);
            }
        }
    }
}

extern "C" void kernel_launch(void* const* d_in, const int* in_sizes, int n_in,
                              void* d_out, int out_size, void* d_ws, size_t ws_size,
                              hipStream_t stream) {
    const float* Ex = (const float*)d_in[0];
    const float* Ey = (const float*)d_in[1];
    float* out = (float*)d_out;
    u16* Xs = (u16*)d_ws;                // 4 MB, panel layout
    u16* Ys = Xs + (size_t)NROWS * DIM;  // 4 MB, panel layout

    hipLaunchKernelGGL(normalize_kernel, dim3(NROWS / 4, 2), dim3(256), 0, stream,
                       Ex, Ey, Xs, Ys, out);
    hipLaunchKernelGGL(gemm_min_kernel, dim3(16 * 16), dim3(512), 0, stream,
                       Xs, Ys, out);
}

// Round 8
// 93.580 us; speedup vs baseline: 1.2381x; 1.2381x over previous
//
#include <hip/hip_runtime.h>
#include <hip/hip_bf16.h>

typedef unsigned short u16;
typedef __attribute__((ext_vector_type(8))) short short8;
typedef __attribute__((ext_vector_type(4))) float floatx4;

#define NROWS 8192
#define DIM 256

__device__ __forceinline__ void atomicMinFloat(float* addr, float val) {
    if (val >= 0.0f) {
        atomicMin((int*)addr, __float_as_int(val));
    } else {
        atomicMax((unsigned int*)addr, __float_as_uint(val));
    }
}

__device__ __forceinline__ u16 f32_to_bf16_rne(float x) {
    unsigned int u = __float_as_uint(x);
    unsigned int r = (u + 0x7fffu + ((u >> 16) & 1u)) >> 16;
    return (u16)r;
}

// C(M) = -logp * exp(logp); quasiconcave in M => rowmin = min(C(minM), C(maxM)).
__device__ __forceinline__ float c_of_m(float m) {
    const float INV_SIG = 1.0f / 0.3f;
    const float KC = 0.28503427f;  // -ln(0.3) - 0.5*ln(2*pi)
    float z = (m - 1.0f) * INV_SIG;
    float logp = fmaf(-0.5f * z, z, KC);
    return -logp * __expf(logp);
}

// 16B async DMA global -> LDS. LDS dest is wave-uniform base + lane*16.
__device__ __forceinline__ void load16(const u16* g, u16* l) {
    __builtin_amdgcn_global_load_lds(
        (__attribute__((address_space(1))) void*)g,
        (__attribute__((address_space(3))) void*)l, 16, 0, 0);
}

// Normalize rows (L2-norm clamped at 1e-8), wave per row, float4 loads.
// BOTH X and Y are written in MFMA fragment ("panel") layout:
//   element (row r, k) -> flat[ ((p*8+kt)*64 + lq*16 + lm)*8 + j ]
//   p=r>>4, lm=r&15, kt=k>>5, lq=(k>>3)&3, j=k&7.
// A fragment load is then base + lane*16B: one coalesced dwordx4.
// Verified end-to-end R5/R11/R14/R15 (absmax 1.5e-5).
__global__ __launch_bounds__(256) void normalize_kernel(const float* __restrict__ Ex,
                                                        const float* __restrict__ Ey,
                                                        u16* __restrict__ Xs,
                                                        u16* __restrict__ Ys,
                                                        float* __restrict__ out) {
    const int t = threadIdx.x;
    const int ln = t & 63;
    const int row = blockIdx.x * 4 + (t >> 6);
    const float* src = (blockIdx.y == 0) ? Ex : Ey;
    u16* dst = (blockIdx.y == 0) ? Xs : Ys;

    float4 v = *(const float4*)(src + (size_t)row * DIM + ln * 4);
    float s = fmaf(v.x, v.x, fmaf(v.y, v.y, fmaf(v.z, v.z, v.w * v.w)));
    #pragma unroll
    for (int m = 32; m >= 1; m >>= 1) s += __shfl_xor(s, m, 64);
    float inv = 1.0f / fmaxf(sqrtf(s), 1e-8f);

    ushort4 o;
    o.x = f32_to_bf16_rne(v.x * inv);
    o.y = f32_to_bf16_rne(v.y * inv);
    o.z = f32_to_bf16_rne(v.z * inv);
    o.w = f32_to_bf16_rne(v.w * inv);

    const int p = row >> 4;
    const int lm = row & 15;
    const int kt = ln >> 3;
    const int lq = (ln >> 1) & 3;
    const int j4 = (ln & 1) * 4;
    const size_t off = ((size_t)((p * 8 + kt) * 64 + lq * 16 + lm)) * 8 + j4;
    *(ushort4*)(dst + off) = o;

    if (blockIdx.y == 0 && ln == 0) out[row] = __uint_as_float(0x7f800000u);  // +inf
}

// R24: single pass restored (R7's double-pass was instrumentation; it
// measured the 2-deep B-register pipeline at ~27-28.7 us/pass vs R6's ~36 ->
// KEEP the pipeline). R7 counters: MfmaUtil 49%, VALUBusy 25%, 4306 cyc/ct
// vs 2483 MFMA floor. The ~1800 cyc/ct overhead = serial fold tail (fold
// runs after the last MFMA, then barrier) + ct-start in-phase stall (all
// waves burst ds_reads post-barrier while the MFMA pipe idles). Fix: fold
// ct-1's acc INSIDE ct's read-latency window -- issue the first 4 B-frag
// reads, fold (pure VALU, no LDS) while they fly, then MFMA. Data deps
// (fold reads acc before kt0's zero-C MFMA overwrites) enforce order;
// per-(row,col) accumulation order unchanged -> bitwise-identical.
// Grid 256 (1 block/CU); XCD swizzle keeps A+B in the local L2.
__global__ void __launch_bounds__(512, 2)
gemm_min_kernel(const u16* __restrict__ Xs,
                const u16* __restrict__ Ys,
                float* __restrict__ out) {
    __shared__ u16 Bs[2][16 * 512];  // 2 x 16 KB

    const int tid = threadIdx.x;
    const int w = tid >> 6;      // 0..7 row-group (64 rows each)
    const int lane = tid & 63;
    const int lq = lane >> 4;
    const int lm = lane & 15;

    // XCD-aware remap (dispatch i -> XCD i&7 round-robin): XCD x gets a
    // 4 row-tile x 8 col-group region. Bijective over the 16x16 grid.
    const int i = blockIdx.x;
    const int x = i & 7;
    const int jj = i >> 3;                      // 0..31 within XCD
    const int rt = (x & 3) * 4 + (jj & 3);      // row-tile 0..15
    const int cgrp = (x >> 2) * 8 + (jj >> 2);  // col-group 0..15

    const int rowStart = rt * 512;
    const int rowPan0 = rt * 32 + w * 4;
    const u16* ybase = Ys + (size_t)cgrp * 32 * 4096;  // advances 8192 u16/ct

    // Stage one 32col x 256k B tile (16 KB = 16 x 1 KB units) via DMA.
    // 8 waves x 2 units; unit u -> (col-panel u>>3, kt u&7); LDS slot u*512
    // so fragment reads are Bs[(cg*8+kt)*512 + lane*8] (b128, conflict-free).
    auto stage1 = [&](int buf, const u16* yb, int iu) {
        const int u = w * 2 + iu;
        load16(yb + (u >> 3) * 4096 + (u & 7) * 512 + lane * 8,
               &Bs[buf][u * 512]);
    };

    short8 a[4][8];
    auto loadA = [&](int kt) {
        #pragma unroll
        for (int rg = 0; rg < 4; ++rg)
            a[rg][kt] = *(const short8*)(
                Xs + ((size_t)(rowPan0 + rg) * 8 + kt) * 512 + lane * 8);
    };

    floatx4 mn4[4], mx4[4];
    #pragma unroll
    for (int rg = 0; rg < 4; ++rg) {
        mn4[rg] = (floatx4){3.4e38f, 3.4e38f, 3.4e38f, 3.4e38f};
        mx4[rg] = (floatx4){-3.4e38f, -3.4e38f, -3.4e38f, -3.4e38f};
    }

    floatx4 acc[4][2];
    const floatx4 FZ = (floatx4){0.0f, 0.0f, 0.0f, 0.0f};

    auto fold = [&]() {
        #pragma unroll
        for (int rg = 0; rg < 4; ++rg)
            #pragma unroll
            for (int cg = 0; cg < 2; ++cg)
                #pragma unroll
                for (int r = 0; r < 4; ++r) {
                    float m = acc[rg][cg][r];
                    mn4[rg][r] = fminf(mn4[rg][r], m);
                    mx4[rg][r] = fmaxf(mx4[rg][r], m);
                }
    };

    // Software-pipelined compute: bfA/bfB alternate, next kt's 2 B-frags
    // issue BEFORE the current kt's 8 MFMAs (counted lgkmcnt covers the
    // latency). dofold=1 folds the PREVIOUS ct's acc right after the first
    // 4 reads are issued -- VALU work inside the LDS-latency window.
    auto compute = [&](int buf, int dofold) {
        const u16* bsb = &Bs[buf][0];
        short8 bfA[2], bfB[2];
        #pragma unroll
        for (int cg = 0; cg < 2; ++cg)
            bfA[cg] = *(const short8*)(bsb + (cg * 8 + 0) * 512 + lane * 8);
        #pragma unroll
        for (int cg = 0; cg < 2; ++cg)
            bfB[cg] = *(const short8*)(bsb + (cg * 8 + 1) * 512 + lane * 8);
        if (dofold) fold();
        #pragma unroll
        for (int k2 = 0; k2 < 4; ++k2) {
            const int ke = 2 * k2;      // even kt, uses bfA
            const int ko = ke + 1;      // odd kt, uses bfB
            if (ke == 0) {
                #pragma unroll
                for (int cg = 0; cg < 2; ++cg)
                    #pragma unroll
                    for (int rg = 0; rg < 4; ++rg)
                        acc[rg][cg] = __builtin_amdgcn_mfma_f32_16x16x32_bf16(
                            a[rg][0], bfA[cg], FZ, 0, 0, 0);
            } else {
                #pragma unroll
                for (int cg = 0; cg < 2; ++cg)
                    #pragma unroll
                    for (int rg = 0; rg < 4; ++rg)
                        acc[rg][cg] = __builtin_amdgcn_mfma_f32_16x16x32_bf16(
                            a[rg][ke], bfA[cg], acc[rg][cg], 0, 0, 0);
            }
            if (ke + 2 < 8) {
                #pragma unroll
                for (int cg = 0; cg < 2; ++cg)
                    bfA[cg] = *(const short8*)(bsb + (cg * 8 + ke + 2) * 512 + lane * 8);
            }
            #pragma unroll
            for (int cg = 0; cg < 2; ++cg)
                #pragma unroll
                for (int rg = 0; rg < 4; ++rg)
                    acc[rg][cg] = __builtin_amdgcn_mfma_f32_16x16x32_bf16(
                        a[rg][ko], bfB[cg], acc[rg][cg], 0, 0, 0);
            if (ko + 2 < 8) {
                #pragma unroll
                for (int cg = 0; cg < 2; ++cg)
                    bfB[cg] = *(const short8*)(bsb + (cg * 8 + ko + 2) * 512 + lane * 8);
            }
        }
    };

    // --- ct = 0, peeled: overlap A prologue with B0 DMA ---
    stage1(0, ybase, 0); stage1(0, ybase, 1);
    loadA(0); loadA(1);
    __syncthreads();         // drains B0 DMA (+ the early A loads)
    stage1(1, ybase + 8192, 0); stage1(1, ybase + 8192, 1);  // prefetch ct=1
    loadA(2); loadA(3); loadA(4); loadA(5); loadA(6); loadA(7);
    compute(0, 0);
    ybase += 8192;

    // --- cts 1..15: steady state; fold of ct-1 happens inside compute ---
    #pragma unroll 1
    for (int ct = 1; ct < 16; ++ct) {
        const int buf = ct & 1;
        __syncthreads();           // drains this ct's B DMA (issued a ct ago)
        if (ct < 15)
            stage1(buf ^ 1, ybase + 8192, 0), stage1(buf ^ 1, ybase + 8192, 1);
        compute(buf, 1);
        ybase += 8192;  // loop-carried: blocks cross-ct hoisting
    }
    fold();  // final ct's acc

    // Single epilogue: quad-lane reduce, eval C twice (quasiconcavity),
    // fire-and-forget atomicMin (no read guard -- R3 post-mortem).
    #pragma unroll
    for (int rg = 0; rg < 4; ++rg) {
        #pragma unroll
        for (int r = 0; r < 4; ++r) {
            float mn = mn4[rg][r];
            float mx = mx4[rg][r];
            #pragma unroll
            for (int mofs = 1; mofs < 16; mofs <<= 1) {
                mn = fminf(mn, __shfl_xor(mn, mofs, 64));
                mx = fmaxf(mx, __shfl_xor(mx, mofs, 64));
            }
            if (lm == 0) {
                float cmin = fminf(c_of_m(mn), c_of_m(mx));
                int row = rowStart + w * 64 + rg * 16 + lq * 4 + r;
                atomicMinFloat(&out[row], cmin);
            }
        }
    }
}

extern "C" void kernel_launch(void* const* d_in, const int* in_sizes, int n_in,
                              void* d_out, int out_size, void* d_ws, size_t ws_size,
                              hipStream_t stream) {
    const float* Ex = (const float*)d_in[0];
    const float* Ey = (const float*)d_in[1];
    float* out = (float*)d_out;
    u16* Xs = (u16*)d_ws;                // 4 MB, panel layout
    u16* Ys = Xs + (size_t)NROWS * DIM;  // 4 MB, panel layout

    hipLaunchKernelGGL(normalize_kernel, dim3(NROWS / 4, 2), dim3(256), 0, stream,
                       Ex, Ey, Xs, Ys, out);
    hipLaunchKernelGGL(gemm_min_kernel, dim3(16 * 16), dim3(512), 0, stream,
                       Xs, Ys, out);
}